// Round 9
// baseline (3290.321 us; speedup 1.0000x reference)
//
#include <hip/hip_runtime.h>
#include <hip/hip_bf16.h>
#include <cstdint>

#define S_LEN 512
#define BATCH 64
#define IDIM  1024
#define HDIM  1024
#define G4    4096
#define NBLK  128   // 4 batch-groups x 32 col-blocks (32 cols each)

typedef __attribute__((ext_vector_type(8))) short short8;
typedef __attribute__((ext_vector_type(4))) float f32x4;
typedef __attribute__((ext_vector_type(4))) unsigned short ushort4v;
typedef __attribute__((ext_vector_type(4))) unsigned int uint4v;

__device__ __forceinline__ unsigned short f2bf(float f){
  union { float f; unsigned u; } v; v.f = f;
  unsigned r = (v.u + 0x7fffu + ((v.u >> 16) & 1u)) >> 16;
  return (unsigned short)r;
}
__device__ __forceinline__ float bf2f(unsigned short s){
  union { unsigned u; float f; } v; v.u = ((unsigned)s) << 16;
  return v.f;
}
__device__ __forceinline__ float sigf(float x){ return 1.0f / (1.0f + __expf(-x)); }
__device__ __forceinline__ float tanhf_fast(float x){
  float e = __expf(2.0f * x);
  return 1.0f - 2.0f / (e + 1.0f);
}
__device__ __forceinline__ f32x4 mfma_bf16(short8 a, short8 b, f32x4 c){
  return __builtin_amdgcn_mfma_f32_16x16x32_bf16(a, b, c, 0, 0, 0);
}
__device__ __forceinline__ float tofloat(float v){ return v; }
__device__ __forceinline__ float tofloat(unsigned short v){ return bf2f(v); }

// ---- LLC-coherent tagged-h accessors (sc0 sc1 = die-level coherence point,
// ---- placement-independent). Internal vmcnt(0) only (round-4 lesson).
// 16 dwordx4: lane's 64 tagged cols = 8 chunks x (2 x 16B), stride 128B.
__device__ __forceinline__ void load16_tagged(const unsigned* p, uint4v* d){
  asm volatile(
    "global_load_dwordx4 %0, %16, off sc0 sc1\n\t"
    "global_load_dwordx4 %1, %16, off offset:16 sc0 sc1\n\t"
    "global_load_dwordx4 %2, %16, off offset:128 sc0 sc1\n\t"
    "global_load_dwordx4 %3, %16, off offset:144 sc0 sc1\n\t"
    "global_load_dwordx4 %4, %16, off offset:256 sc0 sc1\n\t"
    "global_load_dwordx4 %5, %16, off offset:272 sc0 sc1\n\t"
    "global_load_dwordx4 %6, %16, off offset:384 sc0 sc1\n\t"
    "global_load_dwordx4 %7, %16, off offset:400 sc0 sc1\n\t"
    "global_load_dwordx4 %8, %16, off offset:512 sc0 sc1\n\t"
    "global_load_dwordx4 %9, %16, off offset:528 sc0 sc1\n\t"
    "global_load_dwordx4 %10, %16, off offset:640 sc0 sc1\n\t"
    "global_load_dwordx4 %11, %16, off offset:656 sc0 sc1\n\t"
    "global_load_dwordx4 %12, %16, off offset:768 sc0 sc1\n\t"
    "global_load_dwordx4 %13, %16, off offset:784 sc0 sc1\n\t"
    "global_load_dwordx4 %14, %16, off offset:896 sc0 sc1\n\t"
    "global_load_dwordx4 %15, %16, off offset:912 sc0 sc1\n\t"
    "s_waitcnt vmcnt(0)"
    : "=&v"(d[0]), "=&v"(d[1]), "=&v"(d[2]), "=&v"(d[3]),
      "=&v"(d[4]), "=&v"(d[5]), "=&v"(d[6]), "=&v"(d[7]),
      "=&v"(d[8]), "=&v"(d[9]), "=&v"(d[10]), "=&v"(d[11]),
      "=&v"(d[12]), "=&v"(d[13]), "=&v"(d[14]), "=&v"(d[15])
    : "v"(p)
    : "memory");
}
__device__ __forceinline__ void store_dword_bypass(unsigned* p, unsigned v){
  asm volatile("global_store_dword %0, %1, off sc0 sc1" :: "v"(p), "v"(v) : "memory");
}

// xg scalar store helpers (f32 or bf16 storage)
__device__ __forceinline__ void xg_store1(float* p, float v){ *p = v; }
__device__ __forceinline__ void xg_store1(unsigned short* p, float v){ *p = f2bf(v); }

// ---------------------------------------------------------------------------
// prep: pack W_hh into per-(cb,wave,tile,ks) MFMA-B-fragment order (bf16);
// bias sum; seed tagged h(0) (tag 0) into buffer A (replay-safe re-seed).
// Wpack[i]: e=i&7, l=(i>>3)&63, ks=(i>>9)&7, t=(i>>12)&7, w=(i>>15)&3, cb=i>>17
// row_local=t*16+(l&15); col=row_local>>2; gate=row_local&3;
//   -> Whh[gate*1024 + cb*32 + col][w*256 + ks*32 + (l>>4)*8 + e]
// ---------------------------------------------------------------------------
__global__ __launch_bounds__(256) void prep_kernel(
    const float* __restrict__ Whh, const float* __restrict__ bih,
    const float* __restrict__ bhh, const float* __restrict__ h0,
    unsigned short* __restrict__ Wpack, float* __restrict__ biasSum,
    unsigned* __restrict__ hT){
  int i = blockIdx.x * 256 + threadIdx.x;
  if (i < G4) biasSum[i] = bih[i] + bhh[i];
  if (i < BATCH*HDIM) hT[i] = ((unsigned)f2bf(h0[i])) << 16;   // tag 0
  if (i < G4*HDIM){
    int e = i & 7, l = (i >> 3) & 63, ks = (i >> 9) & 7;
    int t = (i >> 12) & 7, w = (i >> 15) & 3, cb = i >> 17;
    int row_local = t * 16 + (l & 15);
    int col = row_local >> 2, gate = row_local & 3;
    int row = gate * HDIM + cb * 32 + col;
    int k = w * 256 + ks * 32 + (l >> 4) * 8 + e;
    Wpack[i] = f2bf(Whh[row * HDIM + k]);
  }
}

// ---------------------------------------------------------------------------
// x_gates GEMM: out[m][n] = sum_k In[m][k] * Wih[n][k] + biasSum[n]
// Packed xg[s][rbid][gate][b16][j32], rbid = (jglob>>5)*4 + (bglob>>4):
// recurrence thread (bl=tid>>5, j=tid&31) reads gate*512 + (bl|bl+8)*32 + j.
// ---------------------------------------------------------------------------
template<typename XGT>
__global__ __launch_bounds__(256) void xg_gemm(
    const float* __restrict__ In, const float* __restrict__ Wih,
    const float* __restrict__ biasSum, XGT* __restrict__ xg){
  __shared__ __align__(16) unsigned short Abuf[128 * 72];
  __shared__ __align__(16) unsigned short Bbuf[128 * 72];
  const int bid = blockIdx.x;
  const int tm = bid >> 5, tn = bid & 31;
  const int bm0 = tm * 128, bn0 = tn * 128;
  const int tid = threadIdx.x;
  const int wid = tid >> 6, l = tid & 63;
  const int wm = wid >> 1, wn = wid & 1;
  const int lr = tid >> 4;
  const int lk = (tid & 15) * 4;

  f32x4 acc[4][4];
  #pragma unroll
  for (int a = 0; a < 4; ++a)
    #pragma unroll
    for (int b = 0; b < 4; ++b) acc[a][b] = (f32x4){0.f, 0.f, 0.f, 0.f};

  for (int kt = 0; kt < 16; ++kt){
    #pragma unroll
    for (int it = 0; it < 8; ++it){
      int r = lr + it * 16;
      f32x4 a4 = *reinterpret_cast<const f32x4*>(&In[(size_t)(bm0 + r) * IDIM + kt * 64 + lk]);
      ushort4v ab; ab[0]=f2bf(a4[0]); ab[1]=f2bf(a4[1]); ab[2]=f2bf(a4[2]); ab[3]=f2bf(a4[3]);
      *reinterpret_cast<ushort4v*>(&Abuf[r * 72 + lk]) = ab;
      f32x4 b4 = *reinterpret_cast<const f32x4*>(&Wih[(size_t)(bn0 + r) * IDIM + kt * 64 + lk]);
      ushort4v bb; bb[0]=f2bf(b4[0]); bb[1]=f2bf(b4[1]); bb[2]=f2bf(b4[2]); bb[3]=f2bf(b4[3]);
      *reinterpret_cast<ushort4v*>(&Bbuf[r * 72 + lk]) = bb;
    }
    __syncthreads();
    #pragma unroll
    for (int ks = 0; ks < 2; ++ks){
      short8 af[4], bfv[4];
      #pragma unroll
      for (int f = 0; f < 4; ++f){
        af[f]  = *reinterpret_cast<const short8*>(&Abuf[(wm*64 + f*16 + (l & 15)) * 72 + ks*32 + (l >> 4) * 8]);
        bfv[f] = *reinterpret_cast<const short8*>(&Bbuf[(wn*64 + f*16 + (l & 15)) * 72 + ks*32 + (l >> 4) * 8]);
      }
      #pragma unroll
      for (int fm = 0; fm < 4; ++fm)
        #pragma unroll
        for (int fn = 0; fn < 4; ++fn)
          acc[fm][fn] = mfma_bf16(af[fm], bfv[fn], acc[fm][fn]);
    }
    __syncthreads();
  }

  const int q = l >> 4, c16 = l & 15;
  #pragma unroll
  for (int fn = 0; fn < 4; ++fn){
    int n = bn0 + wn * 64 + fn * 16 + c16;
    float bias = biasSum[n];
    int gate = n >> 10, jglob = n & 1023;
    int cbb = jglob >> 5, j32 = jglob & 31;
    #pragma unroll
    for (int fm = 0; fm < 4; ++fm){
      int m0 = bm0 + wm * 64 + fm * 16 + q * 4;
      int s = m0 >> 6, bglob = m0 & 63;
      int gg = bglob >> 4, b16 = bglob & 15;   // b16=q*4; r stays in same gg
      int rbid = cbb * 4 + gg;
      size_t base = (((size_t)s * 128 + rbid) * 4 + gate) * 512 + j32;
      f32x4 v = acc[fm][fn];
      #pragma unroll
      for (int r = 0; r < 4; ++r)
        xg_store1(&xg[base + (b16 + r) * 32], v[r] + bias);
    }
  }
}

// ---------------------------------------------------------------------------
// recurrence: 128 persistent blocks = (g: 4 groups of 16 batches) x (cb: 32
// col-blocks of 32 cols). NO barriers, NO flags: h carried as tagged u32
// (bf16<<16 | step). Consumers poll the data until all tags==s; ping-pong
// parity + the read-before-write dependency chain bounds skew to 2 steps.
// W in 256 VGPRs/lane; waves split K (256 each); 1 syncthreads/step.
// ---------------------------------------------------------------------------
template<typename XGT>
__global__ __launch_bounds__(256, 1) void recur_kernel(
    const float* __restrict__ h0, const float* __restrict__ c0,
    const float* __restrict__ ret, const unsigned short* __restrict__ Wpack,
    const XGT* __restrict__ xg, unsigned* __restrict__ hbuf,
    float* __restrict__ out, float* __restrict__ hc_out){
  __shared__ __align__(16) float part[2 * 4 * 16 * 132];  // [p][w][batch16][rl128+pad]

  const int bid = blockIdx.x;
  const int g = bid & 3, cb = bid >> 2;
  const int tid = threadIdx.x;
  const int w = tid >> 6, l = tid & 63;
  const int lm = l & 15, lq = l >> 4, c16 = l & 15;

  // W fragments: 8 N-tiles x 8 ks = 256 VGPRs/lane
  short8 Wf[8][8];
  {
    const short8* wp = reinterpret_cast<const short8*>(Wpack)
                     + (size_t)(cb * 4 + w) * 4096 + l;
    #pragma unroll
    for (int t = 0; t < 8; ++t)
      #pragma unroll
      for (int ks = 0; ks < 8; ++ks)
        Wf[t][ks] = wp[(t * 8 + ks) * 64];
  }

  const int j = tid & 31, bl = tid >> 5;        // col-in-block, batch 0..7
  const int jglob = cb * 32 + j;
  const int bg0 = g * 16 + bl, bg1 = bg0 + 8;   // two batches per thread
  float c0_ = c0[bg0 * HDIM + jglob], h0_ = h0[bg0 * HDIM + jglob];
  float c1_ = c0[bg1 * HDIM + jglob], h1_ = h0[bg1 * HDIM + jglob];
  float r_reg = ret[jglob];

  // xg preload for s=0 (raw, converted at use)
  XGT xr[8];
  {
    const XGT* xp = xg + (size_t)bid * 2048 + bl * 32 + j;
    #pragma unroll
    for (int gate = 0; gate < 4; ++gate){
      xr[gate * 2 + 0] = xp[gate * 512];
      xr[gate * 2 + 1] = xp[gate * 512 + 256];
    }
  }

  int budget = 2000000;   // GLOBAL spin budget: bug -> fast absmax fail, no hang

  for (int s = 0; s < S_LEN; ++s){
    // ---- poll + load tagged h(s) from buf[s&1] (wave's K-slice) ----
    const unsigned* cur = hbuf + (s & 1) * (BATCH * HDIM)
                        + (g * 16 + lm) * HDIM + w * 256 + lq * 8;
    unsigned* nxt = hbuf + ((s + 1) & 1) * (BATCH * HDIM) + g * 16 * HDIM;
    const unsigned tag = (unsigned)s;
    uint4v tv[16];
    for (;;){
      load16_tagged(cur, tv);
      unsigned diff = 0;
      #pragma unroll
      for (int i = 0; i < 16; ++i){
        diff |= (tv[i][0] ^ tag) & 0xffffu;
        diff |= (tv[i][1] ^ tag) & 0xffffu;
        diff |= (tv[i][2] ^ tag) & 0xffffu;
        diff |= (tv[i][3] ^ tag) & 0xffffu;
      }
      if (__all(diff == 0)) break;
      if (--budget < 0) break;
      __builtin_amdgcn_s_sleep(1);
    }

    // ---- repack hi16 -> bf16 short8, MFMA (8 ks x 8 tiles) ----
    f32x4 acc[8];
    #pragma unroll
    for (int t = 0; t < 8; ++t) acc[t] = (f32x4){0.f, 0.f, 0.f, 0.f};
    #pragma unroll
    for (int ks = 0; ks < 8; ++ks){
      union { unsigned u[4]; short8 s8; } hh;
      uint4v a = tv[2 * ks], b = tv[2 * ks + 1];
      hh.u[0] = (a[0] >> 16) | (a[1] & 0xffff0000u);
      hh.u[1] = (a[2] >> 16) | (a[3] & 0xffff0000u);
      hh.u[2] = (b[0] >> 16) | (b[1] & 0xffff0000u);
      hh.u[3] = (b[2] >> 16) | (b[3] & 0xffff0000u);
      #pragma unroll
      for (int t = 0; t < 8; ++t)
        acc[t] = mfma_bf16(hh.s8, Wf[t][ks], acc[t]);
    }

    // ---- partials to LDS: [p][w][batch=lq*4+r][row_local=t*16+c16] ----
    const int pbase = (s & 1) * (4 * 16 * 132);
    #pragma unroll
    for (int t = 0; t < 8; ++t)
      #pragma unroll
      for (int r = 0; r < 4; ++r)
        part[pbase + (w * 16 + lq * 4 + r) * 132 + t * 16 + c16] = acc[t][r];
    __syncthreads();   // single barrier per step (parity double-buffer)

    // ---- reduce 4 waves + xg, gate math for 2 batches ----
    float gv0[4], gv1[4];
    #pragma unroll
    for (int gate = 0; gate < 4; ++gate){
      gv0[gate] = tofloat(xr[gate * 2 + 0]);
      gv1[gate] = tofloat(xr[gate * 2 + 1]);
    }
    #pragma unroll
    for (int ww = 0; ww < 4; ++ww){
      f32x4 p0 = *reinterpret_cast<const f32x4*>(&part[pbase + (ww * 16 + bl) * 132 + j * 4]);
      f32x4 p1 = *reinterpret_cast<const f32x4*>(&part[pbase + (ww * 16 + bl + 8) * 132 + j * 4]);
      #pragma unroll
      for (int gate = 0; gate < 4; ++gate){ gv0[gate] += p0[gate]; gv1[gate] += p1[gate]; }
    }
    const unsigned ntag = (unsigned)(s + 1);
    float hy0, hy1;
    {
      float ig = sigf(gv0[0]), fg = sigf(gv0[1]);
      float gt = tanhf_fast(gv0[2]), og = sigf(gv0[3]);
      float cy = fg * c0_ + ig * gt;
      float hv = og * tanhf_fast(cy);
      hy0 = r_reg * h0_ + (1.0f - r_reg) * hv;
      c0_ = cy; h0_ = hy0;
      store_dword_bypass(&nxt[bl * HDIM + jglob], (((unsigned)f2bf(hy0)) << 16) | ntag);
    }
    {
      float ig = sigf(gv1[0]), fg = sigf(gv1[1]);
      float gt = tanhf_fast(gv1[2]), og = sigf(gv1[3]);
      float cy = fg * c1_ + ig * gt;
      float hv = og * tanhf_fast(cy);
      hy1 = r_reg * h1_ + (1.0f - r_reg) * hv;
      c1_ = cy; h1_ = hy1;
      store_dword_bypass(&nxt[(bl + 8) * HDIM + jglob], (((unsigned)f2bf(hy1)) << 16) | ntag);
    }

    // off-critical-path: out stores + next xg prefetch (plain cached)
    out[((size_t)s * BATCH + bg0) * HDIM + jglob] = hy0;
    out[((size_t)s * BATCH + bg1) * HDIM + jglob] = hy1;
    if (s + 1 < S_LEN){
      const XGT* xp = xg + ((size_t)(s + 1) * 128 + bid) * 2048 + bl * 32 + j;
      #pragma unroll
      for (int gate = 0; gate < 4; ++gate){
        xr[gate * 2 + 0] = xp[gate * 512];
        xr[gate * 2 + 1] = xp[gate * 512 + 256];
      }
    }
  }

  hc_out[bg0 * HDIM + jglob] = h0_;
  hc_out[bg1 * HDIM + jglob] = h1_;
  hc_out[BATCH * HDIM + bg0 * HDIM + jglob] = c0_;
  hc_out[BATCH * HDIM + bg1 * HDIM + jglob] = c1_;
}

// ---------------------------------------------------------------------------
extern "C" void kernel_launch(void* const* d_in, const int* in_sizes, int n_in,
                              void* d_out, int out_size, void* d_ws, size_t ws_size,
                              hipStream_t stream){
  const float* In  = (const float*)d_in[0];
  const float* h0  = (const float*)d_in[1];
  const float* c0  = (const float*)d_in[2];
  const float* Wih = (const float*)d_in[3];
  const float* Whh = (const float*)d_in[4];
  const float* bih = (const float*)d_in[5];
  const float* bhh = (const float*)d_in[6];
  const float* ret = (const float*)d_in[7];
  float* out = (float*)d_out;

  char* ws = (char*)d_ws;
  const size_t off_bias = 0;                     // 16 KB
  const size_t off_h    = 16384;                 // 512 KB: [2][64][1024] u32 tagged
  const size_t off_wp   = off_h + 524288;        // 8 MB
  const size_t off_xg   = off_wp + 8388608;
  const size_t xg_elems = (size_t)S_LEN * G4 * BATCH;
  const size_t need_f32 = off_xg + xg_elems * 4;
  const size_t need_b16 = off_xg + xg_elems * 2;

  float*          biasSum = (float*)(ws + off_bias);
  unsigned*       hbuf    = (unsigned*)(ws + off_h);
  unsigned short* Wpack   = (unsigned short*)(ws + off_wp);

  if (ws_size < need_b16) return;  // cannot run; fail validation loudly

  prep_kernel<<<16384, 256, 0, stream>>>(Whh, bih, bhh, h0, Wpack, biasSum, hbuf);

  float* hc_out = out + (size_t)S_LEN * BATCH * HDIM;
  if (ws_size >= need_f32){
    float* xg = (float*)(ws + off_xg);
    xg_gemm<float><<<8192, 256, 0, stream>>>(In, Wih, biasSum, xg);
    recur_kernel<float><<<NBLK, 256, 0, stream>>>(h0, c0, ret, Wpack, xg, hbuf,
                                                  out, hc_out);
  } else {
    unsigned short* xg = (unsigned short*)(ws + off_xg);
    xg_gemm<unsigned short><<<8192, 256, 0, stream>>>(In, Wih, biasSum, xg);
    recur_kernel<unsigned short><<<NBLK, 256, 0, stream>>>(h0, c0, ret, Wpack, xg, hbuf,
                                                           out, hc_out);
  }
}

// Round 10
// 3247.234 us; speedup vs baseline: 1.0133x; 1.0133x over previous
//
#include <hip/hip_runtime.h>
#include <hip/hip_bf16.h>
#include <cstdint>

#define S_LEN 512
#define BATCH 64
#define IDIM  1024
#define HDIM  1024
#define G4    4096
#define NBLK  128   // 4 batch-groups x 32 col-blocks (32 cols each)
#define NREP  4     // h/flag replication factor (same-line fan-in reduction)

typedef __attribute__((ext_vector_type(8))) short short8;
typedef __attribute__((ext_vector_type(4))) float f32x4;
typedef __attribute__((ext_vector_type(4))) unsigned short ushort4v;
typedef __attribute__((ext_vector_type(4))) unsigned int uint4v;

__device__ __forceinline__ unsigned short f2bf(float f){
  union { float f; unsigned u; } v; v.f = f;
  unsigned r = (v.u + 0x7fffu + ((v.u >> 16) & 1u)) >> 16;
  return (unsigned short)r;
}
__device__ __forceinline__ float bf2f(unsigned short s){
  union { unsigned u; float f; } v; v.u = ((unsigned)s) << 16;
  return v.f;
}
__device__ __forceinline__ float sigf(float x){ return 1.0f / (1.0f + __expf(-x)); }
__device__ __forceinline__ float tanhf_fast(float x){
  float e = __expf(2.0f * x);
  return 1.0f - 2.0f / (e + 1.0f);
}
__device__ __forceinline__ f32x4 mfma_bf16(short8 a, short8 b, f32x4 c){
  return __builtin_amdgcn_mfma_f32_16x16x32_bf16(a, b, c, 0, 0, 0);
}
__device__ __forceinline__ float tofloat(float v){ return v; }
__device__ __forceinline__ float tofloat(unsigned short v){ return bf2f(v); }

// ---- LLC-coherent (sc0 sc1) helpers; internal vmcnt(0) only (round-4 lesson).
__device__ __forceinline__ void load8_bypass(const unsigned short* p, short8* d){
  asm volatile(
    "global_load_dwordx4 %0, %8, off sc0 sc1\n\t"
    "global_load_dwordx4 %1, %8, off offset:64 sc0 sc1\n\t"
    "global_load_dwordx4 %2, %8, off offset:128 sc0 sc1\n\t"
    "global_load_dwordx4 %3, %8, off offset:192 sc0 sc1\n\t"
    "global_load_dwordx4 %4, %8, off offset:256 sc0 sc1\n\t"
    "global_load_dwordx4 %5, %8, off offset:320 sc0 sc1\n\t"
    "global_load_dwordx4 %6, %8, off offset:384 sc0 sc1\n\t"
    "global_load_dwordx4 %7, %8, off offset:448 sc0 sc1\n\t"
    "s_waitcnt vmcnt(0)"
    : "=&v"(d[0]), "=&v"(d[1]), "=&v"(d[2]), "=&v"(d[3]),
      "=&v"(d[4]), "=&v"(d[5]), "=&v"(d[6]), "=&v"(d[7])
    : "v"(p)
    : "memory");
}
__device__ __forceinline__ void store_short_bypass(unsigned short* p, unsigned v){
  asm volatile("global_store_short %0, %1, off sc0 sc1" :: "v"(p), "v"(v) : "memory");
}
__device__ __forceinline__ void store_dword_bypass(unsigned* p, unsigned v){
  asm volatile("global_store_dword %0, %1, off sc0 sc1" :: "v"(p), "v"(v) : "memory");
}
__device__ __forceinline__ uint4v load4_flags_bypass(const unsigned* p){
  uint4v f;
  asm volatile("global_load_dwordx4 %0, %1, off sc0 sc1\n\ts_waitcnt vmcnt(0)"
               : "=&v"(f) : "v"(p) : "memory");
  return f;
}

// xg scalar store helpers (f32 or bf16 storage)
__device__ __forceinline__ void xg_store1(float* p, float v){ *p = v; }
__device__ __forceinline__ void xg_store1(unsigned short* p, float v){ *p = f2bf(v); }

// ---------------------------------------------------------------------------
// prep: pack W_hh into per-(cb,wave,tile,ks) MFMA-B-fragment order (bf16);
// bias sum; seed h(0) bf16 into all NREP replicas of parity-0 buffer.
// Wpack[i]: e=i&7, l=(i>>3)&63, ks=(i>>9)&7, t=(i>>12)&7, w=(i>>15)&3, cb=i>>17
// row_local=t*16+(l&15); col=row_local>>2; gate=row_local&3;
//   -> Whh[gate*1024 + cb*32 + col][w*256 + ks*32 + (l>>4)*8 + e]
// ---------------------------------------------------------------------------
__global__ __launch_bounds__(256) void prep_kernel(
    const float* __restrict__ Whh, const float* __restrict__ bih,
    const float* __restrict__ bhh, const float* __restrict__ h0,
    unsigned short* __restrict__ Wpack, float* __restrict__ biasSum,
    unsigned short* __restrict__ hbuf){
  int i = blockIdx.x * 256 + threadIdx.x;
  if (i < G4) biasSum[i] = bih[i] + bhh[i];
  if (i < BATCH*HDIM){
    unsigned short v = f2bf(h0[i]);
    #pragma unroll
    for (int r = 0; r < NREP; ++r) hbuf[r * (BATCH*HDIM) + i] = v;
  }
  if (i < G4*HDIM){
    int e = i & 7, l = (i >> 3) & 63, ks = (i >> 9) & 7;
    int t = (i >> 12) & 7, w = (i >> 15) & 3, cb = i >> 17;
    int row_local = t * 16 + (l & 15);
    int col = row_local >> 2, gate = row_local & 3;
    int row = gate * HDIM + cb * 32 + col;
    int k = w * 256 + ks * 32 + (l >> 4) * 8 + e;
    Wpack[i] = f2bf(Whh[row * HDIM + k]);
  }
}

// ---------------------------------------------------------------------------
// x_gates GEMM: out[m][n] = sum_k In[m][k] * Wih[n][k] + biasSum[n]
// Packed xg[s][rbid][gate][b16][j32], rbid = (jglob>>5)*4 + (bglob>>4):
// recurrence thread (bl=tid>>5, j=tid&31) reads gate*512 + (bl|bl+8)*32 + j.
// ---------------------------------------------------------------------------
template<typename XGT>
__global__ __launch_bounds__(256) void xg_gemm(
    const float* __restrict__ In, const float* __restrict__ Wih,
    const float* __restrict__ biasSum, XGT* __restrict__ xg){
  __shared__ __align__(16) unsigned short Abuf[128 * 72];
  __shared__ __align__(16) unsigned short Bbuf[128 * 72];
  const int bid = blockIdx.x;
  const int tm = bid >> 5, tn = bid & 31;
  const int bm0 = tm * 128, bn0 = tn * 128;
  const int tid = threadIdx.x;
  const int wid = tid >> 6, l = tid & 63;
  const int wm = wid >> 1, wn = wid & 1;
  const int lr = tid >> 4;
  const int lk = (tid & 15) * 4;

  f32x4 acc[4][4];
  #pragma unroll
  for (int a = 0; a < 4; ++a)
    #pragma unroll
    for (int b = 0; b < 4; ++b) acc[a][b] = (f32x4){0.f, 0.f, 0.f, 0.f};

  for (int kt = 0; kt < 16; ++kt){
    #pragma unroll
    for (int it = 0; it < 8; ++it){
      int r = lr + it * 16;
      f32x4 a4 = *reinterpret_cast<const f32x4*>(&In[(size_t)(bm0 + r) * IDIM + kt * 64 + lk]);
      ushort4v ab; ab[0]=f2bf(a4[0]); ab[1]=f2bf(a4[1]); ab[2]=f2bf(a4[2]); ab[3]=f2bf(a4[3]);
      *reinterpret_cast<ushort4v*>(&Abuf[r * 72 + lk]) = ab;
      f32x4 b4 = *reinterpret_cast<const f32x4*>(&Wih[(size_t)(bn0 + r) * IDIM + kt * 64 + lk]);
      ushort4v bb; bb[0]=f2bf(b4[0]); bb[1]=f2bf(b4[1]); bb[2]=f2bf(b4[2]); bb[3]=f2bf(b4[3]);
      *reinterpret_cast<ushort4v*>(&Bbuf[r * 72 + lk]) = bb;
    }
    __syncthreads();
    #pragma unroll
    for (int ks = 0; ks < 2; ++ks){
      short8 af[4], bfv[4];
      #pragma unroll
      for (int f = 0; f < 4; ++f){
        af[f]  = *reinterpret_cast<const short8*>(&Abuf[(wm*64 + f*16 + (l & 15)) * 72 + ks*32 + (l >> 4) * 8]);
        bfv[f] = *reinterpret_cast<const short8*>(&Bbuf[(wn*64 + f*16 + (l & 15)) * 72 + ks*32 + (l >> 4) * 8]);
      }
      #pragma unroll
      for (int fm = 0; fm < 4; ++fm)
        #pragma unroll
        for (int fn = 0; fn < 4; ++fn)
          acc[fm][fn] = mfma_bf16(af[fm], bfv[fn], acc[fm][fn]);
    }
    __syncthreads();
  }

  const int q = l >> 4, c16 = l & 15;
  #pragma unroll
  for (int fn = 0; fn < 4; ++fn){
    int n = bn0 + wn * 64 + fn * 16 + c16;
    float bias = biasSum[n];
    int gate = n >> 10, jglob = n & 1023;
    int cbb = jglob >> 5, j32 = jglob & 31;
    #pragma unroll
    for (int fm = 0; fm < 4; ++fm){
      int m0 = bm0 + wm * 64 + fm * 16 + q * 4;
      int s = m0 >> 6, bglob = m0 & 63;
      int gg = bglob >> 4, b16 = bglob & 15;   // b16=q*4; r stays in same gg
      int rbid = cbb * 4 + gg;
      size_t base = (((size_t)s * 128 + rbid) * 4 + gate) * 512 + j32;
      f32x4 v = acc[fm][fn];
      #pragma unroll
      for (int r = 0; r < 4; ++r)
        xg_store1(&xg[base + (b16 + r) * 32], v[r] + bias);
    }
  }
}

// ---------------------------------------------------------------------------
// recurrence: 128 persistent blocks = (g: 4 groups of 16 batches) x (cb: 32
// col-blocks of 32 cols). h' stored to NREP=4 replicas; reader uses replica
// cb&3 -> ~8 same-line readers instead of 32. Per-wave flags (one 64B line
// per block, x4 replicas); wave0 polls its replica, syncthreads broadcasts.
// W in ~256 regs/lane; waves split K (256 each); parity-LDS reduce.
// ---------------------------------------------------------------------------
template<typename XGT>
__global__ __launch_bounds__(256, 1) void recur_kernel(
    const float* __restrict__ h0, const float* __restrict__ c0,
    const float* __restrict__ ret, const unsigned short* __restrict__ Wpack,
    const XGT* __restrict__ xg, unsigned short* __restrict__ hbuf,
    float* __restrict__ out, float* __restrict__ hc_out,
    unsigned* __restrict__ flags){
  __shared__ __align__(16) float part[2 * 4 * 16 * 132];  // [p][w][b16][rl128+4]

  const int bid = blockIdx.x;
  const int g = bid & 3, cb = bid >> 2;
  const int tid = threadIdx.x;
  const int w = tid >> 6, l = tid & 63;
  const int lm = l & 15, lq = l >> 4, c16 = l & 15;
  const int rep = cb & 3;

  // W fragments: 8 N-tiles x 8 ks (256 regs/lane, VGPR+AGPR unified file)
  short8 Wf[8][8];
  {
    const short8* wp = reinterpret_cast<const short8*>(Wpack)
                     + (size_t)(cb * 4 + w) * 4096 + l;
    #pragma unroll
    for (int t = 0; t < 8; ++t)
      #pragma unroll
      for (int ks = 0; ks < 8; ++ks)
        Wf[t][ks] = wp[(t * 8 + ks) * 64];
  }

  const int j = tid & 31, bl = tid >> 5;        // col-in-block, batch 0..7
  const int jglob = cb * 32 + j;
  const int bg0 = g * 16 + bl, bg1 = bg0 + 8;   // two batches per thread
  float c0_ = c0[bg0 * HDIM + jglob], h0_ = h0[bg0 * HDIM + jglob];
  float c1_ = c0[bg1 * HDIM + jglob], h1_ = h0[bg1 * HDIM + jglob];
  float r_reg = ret[jglob];

  // xg preload for s=0 (raw, converted at use)
  XGT xr[8];
  {
    const XGT* xp = xg + (size_t)bid * 2048 + bl * 32 + j;
    #pragma unroll
    for (int gate = 0; gate < 4; ++gate){
      xr[gate * 2 + 0] = xp[gate * 512];
      xr[gate * 2 + 1] = xp[gate * 512 + 256];
    }
  }

  int budget = 1000000;   // GLOBAL poll budget: bug -> fast absmax fail, no hang

  for (int s = 0; s < S_LEN; ++s){
    // ---- load h(s) from this block's replica of buf[s&1] ----
    const unsigned short* cur = hbuf
        + ((size_t)((s & 1) * NREP + rep)) * (BATCH * HDIM)
        + (g * 16 + lm) * HDIM + w * 256 + lq * 8;
    short8 hr[8];
    load8_bypass(cur, hr);   // internal vmcnt(0) also drains prev out/xg ops

    // ---- MFMA: 8 K-slices x 8 N-tiles ----
    f32x4 acc[8];
    #pragma unroll
    for (int t = 0; t < 8; ++t) acc[t] = (f32x4){0.f, 0.f, 0.f, 0.f};
    #pragma unroll
    for (int ks = 0; ks < 8; ++ks)
      #pragma unroll
      for (int t = 0; t < 8; ++t)
        acc[t] = mfma_bf16(hr[ks], Wf[t][ks], acc[t]);

    // ---- partials to LDS: [p][w][batch=lq*4+r][row_local=t*16+c16] ----
    const int pbase = (s & 1) * (4 * 16 * 132);
    #pragma unroll
    for (int t = 0; t < 8; ++t)
      #pragma unroll
      for (int r = 0; r < 4; ++r)
        part[pbase + (w * 16 + lq * 4 + r) * 132 + t * 16 + c16] = acc[t][r];
    __syncthreads();   // sync#1 (parity double-buffer keeps this the only
                       // pre-reduce barrier; 2-step skew impossible)

    // ---- reduce 4 waves + xg, gate math for 2 batches ----
    float gv0[4], gv1[4];
    #pragma unroll
    for (int gate = 0; gate < 4; ++gate){
      gv0[gate] = tofloat(xr[gate * 2 + 0]);
      gv1[gate] = tofloat(xr[gate * 2 + 1]);
    }
    #pragma unroll
    for (int ww = 0; ww < 4; ++ww){
      f32x4 p0 = *reinterpret_cast<const f32x4*>(&part[pbase + (ww * 16 + bl) * 132 + j * 4]);
      f32x4 p1 = *reinterpret_cast<const f32x4*>(&part[pbase + (ww * 16 + bl + 8) * 132 + j * 4]);
      #pragma unroll
      for (int gate = 0; gate < 4; ++gate){ gv0[gate] += p0[gate]; gv1[gate] += p1[gate]; }
    }
    const unsigned ntag = (unsigned)(s + 1);
    float hy0, hy1;
    {
      float ig = sigf(gv0[0]), fg = sigf(gv0[1]);
      float gt = tanhf_fast(gv0[2]), og = sigf(gv0[3]);
      float cy = fg * c0_ + ig * gt;
      float hv = og * tanhf_fast(cy);
      hy0 = r_reg * h0_ + (1.0f - r_reg) * hv;
      c0_ = cy; h0_ = hy0;
    }
    {
      float ig = sigf(gv1[0]), fg = sigf(gv1[1]);
      float gt = tanhf_fast(gv1[2]), og = sigf(gv1[3]);
      float cy = fg * c1_ + ig * gt;
      float hv = og * tanhf_fast(cy);
      hy1 = r_reg * h1_ + (1.0f - r_reg) * hv;
      c1_ = cy; h1_ = hy1;
    }

    // ---- store h' to all replicas of buf[(s+1)&1] ----
    const unsigned v0 = (unsigned)f2bf(hy0), v1 = (unsigned)f2bf(hy1);
    #pragma unroll
    for (int r = 0; r < NREP; ++r){
      unsigned short* nb = hbuf
          + ((size_t)(((s + 1) & 1) * NREP + r)) * (BATCH * HDIM)
          + g * 16 * HDIM;
      store_short_bypass(&nb[bl * HDIM + jglob], v0);
      store_short_bypass(&nb[(bl + 8) * HDIM + jglob], v1);
    }

    // ---- per-wave drain + replicated flag, wave0 polls own replica ----
    asm volatile("s_waitcnt vmcnt(0)" ::: "memory");  // wave's h' at LLC
    if (l == 0){
      #pragma unroll
      for (int r = 0; r < NREP; ++r)
        store_dword_bypass(&flags[(r * 4 + g) * 512 + cb * 16 + w], ntag);
    }
    if (w == 0 && l < 32){          // lane l polls block l's flag line
      const unsigned* fp = flags + (rep * 4 + g) * 512 + (l << 4);
      for (;;){
        uint4v f = load4_flags_bypass(fp);
        if (__all(f[0] >= ntag && f[1] >= ntag && f[2] >= ntag && f[3] >= ntag)) break;
        if (--budget < 0) break;
        __builtin_amdgcn_s_sleep(1);
      }
    }
    __syncthreads();   // sync#2: broadcast barrier-passed to all waves

    // off-critical-path: out stores + next xg prefetch (plain cached)
    out[((size_t)s * BATCH + bg0) * HDIM + jglob] = hy0;
    out[((size_t)s * BATCH + bg1) * HDIM + jglob] = hy1;
    if (s + 1 < S_LEN){
      const XGT* xp = xg + ((size_t)(s + 1) * 128 + bid) * 2048 + bl * 32 + j;
      #pragma unroll
      for (int gate = 0; gate < 4; ++gate){
        xr[gate * 2 + 0] = xp[gate * 512];
        xr[gate * 2 + 1] = xp[gate * 512 + 256];
      }
    }
  }

  hc_out[bg0 * HDIM + jglob] = h0_;
  hc_out[bg1 * HDIM + jglob] = h1_;
  hc_out[BATCH * HDIM + bg0 * HDIM + jglob] = c0_;
  hc_out[BATCH * HDIM + bg1 * HDIM + jglob] = c1_;
}

// ---------------------------------------------------------------------------
extern "C" void kernel_launch(void* const* d_in, const int* in_sizes, int n_in,
                              void* d_out, int out_size, void* d_ws, size_t ws_size,
                              hipStream_t stream){
  const float* In  = (const float*)d_in[0];
  const float* h0  = (const float*)d_in[1];
  const float* c0  = (const float*)d_in[2];
  const float* Wih = (const float*)d_in[3];
  const float* Whh = (const float*)d_in[4];
  const float* bih = (const float*)d_in[5];
  const float* bhh = (const float*)d_in[6];
  const float* ret = (const float*)d_in[7];
  float* out = (float*)d_out;

  char* ws = (char*)d_ws;
  const size_t off_flags = 0;                    // 32 KB (4 reps x 4 g x 32 x 64B)
  const size_t off_bias  = 32768;                // 16 KB
  const size_t off_h     = 49152;                // 1 MB: [2][4][64][1024] bf16
  const size_t off_wp    = off_h + 1048576;      // 8 MB
  const size_t off_xg    = off_wp + 8388608;
  const size_t xg_elems  = (size_t)S_LEN * G4 * BATCH;
  const size_t need_f32  = off_xg + xg_elems * 4;
  const size_t need_b16  = off_xg + xg_elems * 2;

  unsigned*       flags   = (unsigned*)(ws + off_flags);
  float*          biasSum = (float*)(ws + off_bias);
  unsigned short* hbuf    = (unsigned short*)(ws + off_h);
  unsigned short* Wpack   = (unsigned short*)(ws + off_wp);

  if (ws_size < need_b16) return;  // cannot run; fail validation loudly

  (void)hipMemsetAsync(ws + off_flags, 0, 32768, stream);
  prep_kernel<<<16384, 256, 0, stream>>>(Whh, bih, bhh, h0, Wpack, biasSum, hbuf);

  float* hc_out = out + (size_t)S_LEN * BATCH * HDIM;
  if (ws_size >= need_f32){
    float* xg = (float*)(ws + off_xg);
    xg_gemm<float><<<8192, 256, 0, stream>>>(In, Wih, biasSum, xg);
    recur_kernel<float><<<NBLK, 256, 0, stream>>>(h0, c0, ret, Wpack, xg, hbuf,
                                                  out, hc_out, flags);
  } else {
    unsigned short* xg = (unsigned short*)(ws + off_xg);
    xg_gemm<unsigned short><<<8192, 256, 0, stream>>>(In, Wih, biasSum, xg);
    recur_kernel<unsigned short><<<NBLK, 256, 0, stream>>>(h0, c0, ret, Wpack, xg, hbuf,
                                                           out, hc_out, flags);
  }
}

// Round 11
// 2646.852 us; speedup vs baseline: 1.2431x; 1.2268x over previous
//
#include <hip/hip_runtime.h>
#include <hip/hip_bf16.h>
#include <cstdint>

#define S_LEN 512
#define BATCH 64
#define IDIM  1024
#define HDIM  1024
#define G4    4096
#define NBLK  256   // recurrence grid: 4 batch-groups x 64 col-blocks

typedef __attribute__((ext_vector_type(8))) short short8;
typedef __attribute__((ext_vector_type(8))) unsigned short ushort8;
typedef __attribute__((ext_vector_type(4))) float f32x4;
typedef __attribute__((ext_vector_type(4))) unsigned short ushort4v;
typedef __attribute__((ext_vector_type(4))) unsigned int uint4v;

__device__ __forceinline__ unsigned short f2bf(float f){
  union { float f; unsigned u; } v; v.f = f;
  unsigned r = (v.u + 0x7fffu + ((v.u >> 16) & 1u)) >> 16;
  return (unsigned short)r;
}
__device__ __forceinline__ float bf2f(unsigned short s){
  union { unsigned u; float f; } v; v.u = ((unsigned)s) << 16;
  return v.f;
}
__device__ __forceinline__ float sigf(float x){ return 1.0f / (1.0f + __expf(-x)); }
__device__ __forceinline__ float tanhf_fast(float x){
  float e = __expf(2.0f * x);
  return 1.0f - 2.0f / (e + 1.0f);
}
__device__ __forceinline__ f32x4 mfma_bf16(short8 a, short8 b, f32x4 c){
  return __builtin_amdgcn_mfma_f32_16x16x32_bf16(a, b, c, 0, 0, 0);
}

// ---- LLC-coherent (sc0 sc1) helpers; internal vmcnt(0) only (round-4 lesson).
// Combined per-step load: 4 xg loads (cached path, issued FIRST) + 8 h loads
// (sc0sc1). One internal vmcnt(0): latencies overlap (max, not sum).
__device__ __forceinline__ void load_step(const float* xp, const unsigned short* hp,
                                          float* xv, short8* hr){
  asm volatile(
    "global_load_dword %0, %12, off\n\t"
    "global_load_dword %1, %12, off offset:1024\n\t"
    "global_load_dword %2, %12, off offset:2048\n\t"
    "global_load_dword %3, %12, off offset:3072\n\t"
    "global_load_dwordx4 %4, %13, off sc0 sc1\n\t"
    "global_load_dwordx4 %5, %13, off offset:64 sc0 sc1\n\t"
    "global_load_dwordx4 %6, %13, off offset:128 sc0 sc1\n\t"
    "global_load_dwordx4 %7, %13, off offset:192 sc0 sc1\n\t"
    "global_load_dwordx4 %8, %13, off offset:256 sc0 sc1\n\t"
    "global_load_dwordx4 %9, %13, off offset:320 sc0 sc1\n\t"
    "global_load_dwordx4 %10, %13, off offset:384 sc0 sc1\n\t"
    "global_load_dwordx4 %11, %13, off offset:448 sc0 sc1\n\t"
    "s_waitcnt vmcnt(0)"
    : "=&v"(xv[0]), "=&v"(xv[1]), "=&v"(xv[2]), "=&v"(xv[3]),
      "=&v"(hr[0]), "=&v"(hr[1]), "=&v"(hr[2]), "=&v"(hr[3]),
      "=&v"(hr[4]), "=&v"(hr[5]), "=&v"(hr[6]), "=&v"(hr[7])
    : "v"(xp), "v"(hp)
    : "memory");
}
__device__ __forceinline__ void load_step(const unsigned short* xp, const unsigned short* hp,
                                          float* xv, short8* hr){
  unsigned u0, u1, u2, u3;
  asm volatile(
    "global_load_ushort %0, %12, off\n\t"
    "global_load_ushort %1, %12, off offset:512\n\t"
    "global_load_ushort %2, %12, off offset:1024\n\t"
    "global_load_ushort %3, %12, off offset:1536\n\t"
    "global_load_dwordx4 %4, %13, off sc0 sc1\n\t"
    "global_load_dwordx4 %5, %13, off offset:64 sc0 sc1\n\t"
    "global_load_dwordx4 %6, %13, off offset:128 sc0 sc1\n\t"
    "global_load_dwordx4 %7, %13, off offset:192 sc0 sc1\n\t"
    "global_load_dwordx4 %8, %13, off offset:256 sc0 sc1\n\t"
    "global_load_dwordx4 %9, %13, off offset:320 sc0 sc1\n\t"
    "global_load_dwordx4 %10, %13, off offset:384 sc0 sc1\n\t"
    "global_load_dwordx4 %11, %13, off offset:448 sc0 sc1\n\t"
    "s_waitcnt vmcnt(0)"
    : "=&v"(u0), "=&v"(u1), "=&v"(u2), "=&v"(u3),
      "=&v"(hr[0]), "=&v"(hr[1]), "=&v"(hr[2]), "=&v"(hr[3]),
      "=&v"(hr[4]), "=&v"(hr[5]), "=&v"(hr[6]), "=&v"(hr[7])
    : "v"(xp), "v"(hp)
    : "memory");
  xv[0] = bf2f((unsigned short)u0); xv[1] = bf2f((unsigned short)u1);
  xv[2] = bf2f((unsigned short)u2); xv[3] = bf2f((unsigned short)u3);
}
__device__ __forceinline__ void store_short_bypass(unsigned short* p, unsigned v){
  asm volatile("global_store_short %0, %1, off sc0 sc1" :: "v"(p), "v"(v) : "memory");
}
__device__ __forceinline__ void store_dword_bypass(unsigned* p, unsigned v){
  asm volatile("global_store_dword %0, %1, off sc0 sc1" :: "v"(p), "v"(v) : "memory");
}
__device__ __forceinline__ uint4v load4_flags_bypass(const unsigned* p){
  uint4v f;
  asm volatile("global_load_dwordx4 %0, %1, off sc0 sc1\n\ts_waitcnt vmcnt(0)"
               : "=&v"(f) : "v"(p) : "memory");
  return f;
}

// xg scalar store helpers (f32 or bf16 storage)
__device__ __forceinline__ void xg_store1(float* p, float v){ *p = v; }
__device__ __forceinline__ void xg_store1(unsigned short* p, float v){ *p = f2bf(v); }

// ---------------------------------------------------------------------------
// convert: In (33.5M f32) + Wih (4.2M f32) -> bf16, vectorized x4.
// grid 36864 x 256: 9,437,184 threads x 4 = 37,748,736 elements exactly.
// ---------------------------------------------------------------------------
__global__ __launch_bounds__(256) void convert_kernel(
    const float* __restrict__ In, const float* __restrict__ Wih,
    unsigned short* __restrict__ InB, unsigned short* __restrict__ WihB){
  size_t i = ((size_t)blockIdx.x * 256 + threadIdx.x) * 4;
  if (i < (size_t)33554432){
    f32x4 v = *reinterpret_cast<const f32x4*>(&In[i]);
    ushort4v u; u[0]=f2bf(v[0]); u[1]=f2bf(v[1]); u[2]=f2bf(v[2]); u[3]=f2bf(v[3]);
    *reinterpret_cast<ushort4v*>(&InB[i]) = u;
  } else {
    size_t k = i - (size_t)33554432;
    f32x4 v = *reinterpret_cast<const f32x4*>(&Wih[k]);
    ushort4v u; u[0]=f2bf(v[0]); u[1]=f2bf(v[1]); u[2]=f2bf(v[2]); u[3]=f2bf(v[3]);
    *reinterpret_cast<ushort4v*>(&WihB[k]) = u;
  }
}

// ---------------------------------------------------------------------------
// prep: pack W_hh into per-(cb,wave,gate,ks) MFMA-B-fragment order (bf16).
// Wpack[i]: e=i&7, l=(i>>3)&63, ks=(i>>9)&7, gate=(i>>12)&3, w=(i>>14)&3, cb=i>>16
//   -> Whh[gate*1024 + cb*16 + (l&15)][w*256 + ks*32 + (l>>4)*8 + e]
// ---------------------------------------------------------------------------
__global__ __launch_bounds__(256) void prep_kernel(
    const float* __restrict__ Whh, const float* __restrict__ bih,
    const float* __restrict__ bhh, const float* __restrict__ h0,
    unsigned short* __restrict__ Wpack, float* __restrict__ biasSum,
    unsigned short* __restrict__ hA){
  int i = blockIdx.x * 256 + threadIdx.x;
  if (i < G4) biasSum[i] = bih[i] + bhh[i];
  if (i < BATCH*HDIM) hA[i] = f2bf(h0[i]);
  if (i < G4*HDIM){
    int e = i & 7, l = (i >> 3) & 63, ks = (i >> 9) & 7;
    int gate = (i >> 12) & 3, w = (i >> 14) & 3, cb = i >> 16;
    int row = gate * HDIM + cb * 16 + (l & 15);
    int k = w * 256 + ks * 32 + (l >> 4) * 8 + e;
    Wpack[i] = f2bf(Whh[row * HDIM + k]);
  }
}

// ---------------------------------------------------------------------------
// x_gates GEMM (bf16 inputs): out[m][n] = sum_k InB[m][k]*WihB[n][k] + biasSum[n]
// Staging is pure 16B bf16 copies (no convert); fragment reads & packed
// epilogue identical to round 7: xg[s][rbid][gate][bl][jl].
// ---------------------------------------------------------------------------
template<typename XGT>
__global__ __launch_bounds__(256) void xg_gemm(
    const unsigned short* __restrict__ InB, const unsigned short* __restrict__ WihB,
    const float* __restrict__ biasSum, XGT* __restrict__ xg){
  __shared__ __align__(16) unsigned short Abuf[128 * 72];
  __shared__ __align__(16) unsigned short Bbuf[128 * 72];
  const int bid = blockIdx.x;
  const int tm = bid >> 5, tn = bid & 31;
  const int bm0 = tm * 128, bn0 = tn * 128;
  const int tid = threadIdx.x;
  const int wid = tid >> 6, l = tid & 63;
  const int wm = wid >> 1, wn = wid & 1;
  const int sr = tid >> 3;          // staging row 0..31 (+32/iter)
  const int sk = (tid & 7) * 8;     // staging k offset (8 bf16 = 16B)

  f32x4 acc[4][4];
  #pragma unroll
  for (int a = 0; a < 4; ++a)
    #pragma unroll
    for (int b = 0; b < 4; ++b) acc[a][b] = (f32x4){0.f, 0.f, 0.f, 0.f};

  for (int kt = 0; kt < 16; ++kt){
    #pragma unroll
    for (int it = 0; it < 4; ++it){
      int r = sr + it * 32;
      *reinterpret_cast<ushort8*>(&Abuf[r * 72 + sk]) =
        *reinterpret_cast<const ushort8*>(&InB[(size_t)(bm0 + r) * IDIM + kt * 64 + sk]);
      *reinterpret_cast<ushort8*>(&Bbuf[r * 72 + sk]) =
        *reinterpret_cast<const ushort8*>(&WihB[(size_t)(bn0 + r) * IDIM + kt * 64 + sk]);
    }
    __syncthreads();
    #pragma unroll
    for (int ks = 0; ks < 2; ++ks){
      short8 af[4], bfv[4];
      #pragma unroll
      for (int f = 0; f < 4; ++f){
        af[f]  = *reinterpret_cast<const short8*>(&Abuf[(wm*64 + f*16 + (l & 15)) * 72 + ks*32 + (l >> 4) * 8]);
        bfv[f] = *reinterpret_cast<const short8*>(&Bbuf[(wn*64 + f*16 + (l & 15)) * 72 + ks*32 + (l >> 4) * 8]);
      }
      #pragma unroll
      for (int fm = 0; fm < 4; ++fm)
        #pragma unroll
        for (int fn = 0; fn < 4; ++fn)
          acc[fm][fn] = mfma_bf16(af[fm], bfv[fn], acc[fm][fn]);
    }
    __syncthreads();
  }

  const int q = l >> 4, c16 = l & 15;
  #pragma unroll
  for (int fn = 0; fn < 4; ++fn){
    int n = bn0 + wn * 64 + fn * 16 + c16;
    float bias = biasSum[n];
    int gate = n >> 10, jglob = n & 1023;
    int cb = jglob >> 4, jl = jglob & 15;
    #pragma unroll
    for (int fm = 0; fm < 4; ++fm){
      int m0 = bm0 + wm * 64 + fm * 16 + q * 4;
      int s = m0 >> 6, bglob = m0 & 63;
      int g = bglob >> 4, bl0 = bglob & 15;
      int rbid = g * 64 + cb;
      size_t base = (((size_t)s * 256 + rbid) * 4 + gate) * 256;
      f32x4 v = acc[fm][fn];
      #pragma unroll
      for (int r = 0; r < 4; ++r)
        xg_store1(&xg[base + (bl0 + r) * 16 + jl], v[r] + bias);
    }
  }
}

// ---------------------------------------------------------------------------
// recurrence: ROUND-7 VERBATIM (best measured: 2236 us). 256 blocks =
// (g: 4 batch-groups) x (cb: 64 col-blocks). Per-group barrier; per-wave
// flags one 64B line per block; combined xg+h load; W B-frags in VGPRs.
// ---------------------------------------------------------------------------
template<typename XGT>
__global__ __launch_bounds__(256, 1) void recur_kernel(
    const float* __restrict__ h0, const float* __restrict__ c0,
    const float* __restrict__ ret, const unsigned short* __restrict__ Wpack,
    const XGT* __restrict__ xg, unsigned short* __restrict__ hA,
    unsigned short* __restrict__ hB, float* __restrict__ out,
    float* __restrict__ hc_out, unsigned* __restrict__ flags){
  __shared__ float part[16 * 272];   // [w*4+gate]*272 + m*17 + n

  const int bid = blockIdx.x;
  const int cb = bid & 63, g = bid >> 6;
  const int tid = threadIdx.x;
  const int w = tid >> 6, l = tid & 63;
  const int lm = l & 15, lq = l >> 4;

  // W fragments for this (cb, wave): 4 gates x 8 ks, 128 VGPRs/lane
  short8 Wf[4][8];
  {
    const short8* wp = reinterpret_cast<const short8*>(Wpack)
                     + (size_t)(cb * 4 + w) * 2048 + l;
    #pragma unroll
    for (int gate = 0; gate < 4; ++gate)
      #pragma unroll
      for (int ks = 0; ks < 8; ++ks)
        Wf[gate][ks] = wp[(gate * 8 + ks) * 64];
  }

  const int bl = tid >> 4, j = tid & 15;   // batch-in-group, col-in-block
  const int bglob = g * 16 + bl, jglob = cb * 16 + j;
  float c_reg = c0[bglob * HDIM + jglob];
  float h_reg = h0[bglob * HDIM + jglob];
  float r_reg = ret[jglob];

  // flags: one 64B line per block: gflags[cb*16 + w]
  unsigned* gflags = flags + g * 1024;

  for (int s = 0; s < S_LEN; ++s){
    const unsigned short* cur = (s & 1) ? hB : hA;
    unsigned short* nxt = (s & 1) ? hA : hB;

    // combined load: xg[s] (HBM, issued first) + h (LLC), single vmcnt(0)
    const unsigned short* hp = cur + (size_t)(g * 16 + lm) * HDIM + w * 256 + lq * 8;
    const XGT* xp = xg + ((size_t)s * 256 + bid) * 1024 + tid;
    float xv[4];
    short8 hr[8];
    load_step(xp, hp, xv, hr);

    f32x4 acc[4];
    #pragma unroll
    for (int gate = 0; gate < 4; ++gate) acc[gate] = (f32x4){0.f, 0.f, 0.f, 0.f};
    #pragma unroll
    for (int ks = 0; ks < 8; ++ks){
      acc[0] = mfma_bf16(hr[ks], Wf[0][ks], acc[0]);
      acc[1] = mfma_bf16(hr[ks], Wf[1][ks], acc[1]);
      acc[2] = mfma_bf16(hr[ks], Wf[2][ks], acc[2]);
      acc[3] = mfma_bf16(hr[ks], Wf[3][ks], acc[3]);
    }

    // partials to LDS: D layout col=lane&15, row=(lane>>4)*4+r
    #pragma unroll
    for (int gate = 0; gate < 4; ++gate)
      #pragma unroll
      for (int r = 0; r < 4; ++r)
        part[(w * 4 + gate) * 272 + (lq * 4 + r) * 17 + lm] = acc[gate][r];
    __syncthreads();   // sync#1 (nothing pending in vmcnt now)

    // reduce + gate math; c,h in registers of thread (bl,j)
    float gv[4];
    #pragma unroll
    for (int gate = 0; gate < 4; ++gate){
      float sum = xv[gate];
      #pragma unroll
      for (int ww = 0; ww < 4; ++ww)
        sum += part[(ww * 4 + gate) * 272 + bl * 17 + j];
      gv[gate] = sum;
    }
    float ig = sigf(gv[0]), fg = sigf(gv[1]);
    float gt = tanhf_fast(gv[2]), og = sigf(gv[3]);
    float cy = fg * c_reg + ig * gt;
    float hy = og * tanhf_fast(cy);
    hy = r_reg * h_reg + (1.0f - r_reg) * hy;
    c_reg = cy; h_reg = hy;
    // coalesced h' store: 16 consecutive lanes -> 16 consecutive shorts (32B)
    store_short_bypass(&nxt[bglob * HDIM + jglob], (unsigned)f2bf(hy));

    // ---- per-group barrier: per-wave drain + per-wave flag, wave 0 polls ----
    asm volatile("s_waitcnt vmcnt(0)" ::: "memory");  // own wave's h' at LLC
    const unsigned tgt = (unsigned)(s + 1);
    if (l == 0)
      store_dword_bypass(&gflags[cb * 16 + w], tgt);  // wave arrival
    if (w == 0){                    // wave 0: lane l polls block l's flag line
      const unsigned* fp = gflags + (l << 4);
      unsigned spins = 0;
      for (;;){
        uint4v f = load4_flags_bypass(fp);
        if (f[0] >= tgt && f[1] >= tgt && f[2] >= tgt && f[3] >= tgt) break;
        __builtin_amdgcn_s_sleep(1);      // backoff: cut poll read pressure
        if (++spins > 50000000u) break;   // safety bailout, never expected
      }
    }
    __syncthreads();   // sync#2: all waves see the barrier passed

    // out[] store AFTER the barrier: retires under next step's loads
    out[((size_t)s * BATCH + bglob) * HDIM + jglob] = h_reg;
  }

  hc_out[bglob * HDIM + jglob] = h_reg;
  hc_out[BATCH * HDIM + bglob * HDIM + jglob] = c_reg;
}

// ---------------------------------------------------------------------------
extern "C" void kernel_launch(void* const* d_in, const int* in_sizes, int n_in,
                              void* d_out, int out_size, void* d_ws, size_t ws_size,
                              hipStream_t stream){
  const float* In  = (const float*)d_in[0];
  const float* h0  = (const float*)d_in[1];
  const float* c0  = (const float*)d_in[2];
  const float* Wih = (const float*)d_in[3];
  const float* Whh = (const float*)d_in[4];
  const float* bih = (const float*)d_in[5];
  const float* bhh = (const float*)d_in[6];
  const float* ret = (const float*)d_in[7];
  float* out = (float*)d_out;

  char* ws = (char*)d_ws;
  const size_t off_flags = 0;                          // 16 KB (4 groups x 4 KB)
  const size_t off_bias  = 16384;                      // 16 KB
  const size_t off_hA    = 32768;                      // 128 KB
  const size_t off_hB    = off_hA + 131072;
  const size_t off_wp    = off_hB + 131072;            // 8 MB
  const size_t off_inb   = off_wp + 8388608;           // 64 MB (In bf16)
  const size_t off_wihb  = off_inb + 67108864;         // 8 MB (Wih bf16)
  const size_t off_xg    = off_wihb + 8388608;
  const size_t xg_elems  = (size_t)S_LEN * G4 * BATCH;
  const size_t need_f32  = off_xg + xg_elems * 4;
  const size_t need_b16  = off_xg + xg_elems * 2;

  unsigned*       flags   = (unsigned*)(ws + off_flags);
  float*          biasSum = (float*)(ws + off_bias);
  unsigned short* hA      = (unsigned short*)(ws + off_hA);
  unsigned short* hB      = (unsigned short*)(ws + off_hB);
  unsigned short* Wpack   = (unsigned short*)(ws + off_wp);
  unsigned short* InB     = (unsigned short*)(ws + off_inb);
  unsigned short* WihB    = (unsigned short*)(ws + off_wihb);

  if (ws_size < need_b16) return;  // cannot run; fail validation loudly

  (void)hipMemsetAsync(ws + off_flags, 0, 16384, stream);
  convert_kernel<<<36864, 256, 0, stream>>>(In, Wih, InB, WihB);
  prep_kernel<<<16384, 256, 0, stream>>>(Whh, bih, bhh, h0, Wpack, biasSum, hA);

  float* hc_out = out + (size_t)S_LEN * BATCH * HDIM;
  if (ws_size >= need_f32){
    float* xg = (float*)(ws + off_xg);
    xg_gemm<float><<<8192, 256, 0, stream>>>(InB, WihB, biasSum, xg);
    recur_kernel<float><<<NBLK, 256, 0, stream>>>(h0, c0, ret, Wpack, xg, hA, hB,
                                                  out, hc_out, flags);
  } else {
    unsigned short* xg = (unsigned short*)(ws + off_xg);
    xg_gemm<unsigned short><<<8192, 256, 0, stream>>>(InB, WihB, biasSum, xg);
    recur_kernel<unsigned short><<<NBLK, 256, 0, stream>>>(h0, c0, ret, Wpack, xg,
                                                           hA, hB, out, hc_out, flags);
  }
}

// Round 12
// 2377.099 us; speedup vs baseline: 1.3842x; 1.1135x over previous
//
#include <hip/hip_runtime.h>
#include <hip/hip_bf16.h>
#include <cstdint>

#define S_LEN 512
#define BATCH 64
#define IDIM  1024
#define HDIM  1024
#define G4    4096
#define NBLK  256   // recurrence grid: 4 batch-groups x 64 col-blocks

typedef __attribute__((ext_vector_type(8))) short short8;
typedef __attribute__((ext_vector_type(8))) unsigned short ushort8;
typedef __attribute__((ext_vector_type(4))) float f32x4;
typedef __attribute__((ext_vector_type(4))) unsigned short ushort4v;
typedef __attribute__((ext_vector_type(4))) unsigned int uint4v;

__device__ __forceinline__ unsigned short f2bf(float f){
  union { float f; unsigned u; } v; v.f = f;
  unsigned r = (v.u + 0x7fffu + ((v.u >> 16) & 1u)) >> 16;
  return (unsigned short)r;
}
__device__ __forceinline__ float bf2f(unsigned short s){
  union { unsigned u; float f; } v; v.u = ((unsigned)s) << 16;
  return v.f;
}
__device__ __forceinline__ float sigf(float x){ return 1.0f / (1.0f + __expf(-x)); }
__device__ __forceinline__ float tanhf_fast(float x){
  float e = __expf(2.0f * x);
  return 1.0f - 2.0f / (e + 1.0f);
}
__device__ __forceinline__ f32x4 mfma_bf16(short8 a, short8 b, f32x4 c){
  return __builtin_amdgcn_mfma_f32_16x16x32_bf16(a, b, c, 0, 0, 0);
}

// ---- LLC-coherent (sc0 sc1) helpers; internal vmcnt(0) only (round-4 lesson).
__device__ __forceinline__ void load8_bypass(const unsigned short* p, short8* d){
  asm volatile(
    "global_load_dwordx4 %0, %8, off sc0 sc1\n\t"
    "global_load_dwordx4 %1, %8, off offset:64 sc0 sc1\n\t"
    "global_load_dwordx4 %2, %8, off offset:128 sc0 sc1\n\t"
    "global_load_dwordx4 %3, %8, off offset:192 sc0 sc1\n\t"
    "global_load_dwordx4 %4, %8, off offset:256 sc0 sc1\n\t"
    "global_load_dwordx4 %5, %8, off offset:320 sc0 sc1\n\t"
    "global_load_dwordx4 %6, %8, off offset:384 sc0 sc1\n\t"
    "global_load_dwordx4 %7, %8, off offset:448 sc0 sc1\n\t"
    "s_waitcnt vmcnt(0)"
    : "=&v"(d[0]), "=&v"(d[1]), "=&v"(d[2]), "=&v"(d[3]),
      "=&v"(d[4]), "=&v"(d[5]), "=&v"(d[6]), "=&v"(d[7])
    : "v"(p)
    : "memory");
}
__device__ __forceinline__ void store_short_bypass(unsigned short* p, unsigned v){
  asm volatile("global_store_short %0, %1, off sc0 sc1" :: "v"(p), "v"(v) : "memory");
}
__device__ __forceinline__ void store_dword_bypass(unsigned* p, unsigned v){
  asm volatile("global_store_dword %0, %1, off sc0 sc1" :: "v"(p), "v"(v) : "memory");
}
__device__ __forceinline__ uint4v load4_flags_bypass(const unsigned* p){
  uint4v f;
  asm volatile("global_load_dwordx4 %0, %1, off sc0 sc1\n\ts_waitcnt vmcnt(0)"
               : "=&v"(f) : "v"(p) : "memory");
  return f;
}

// ---------------------------------------------------------------------------
// convert: In (33.5M f32) -> bf16, vectorized x4. 32768 blocks x 256 x 4.
// ---------------------------------------------------------------------------
__global__ __launch_bounds__(256) void convert_kernel(
    const float* __restrict__ In, unsigned short* __restrict__ InB){
  size_t i = ((size_t)blockIdx.x * 256 + threadIdx.x) * 4;
  f32x4 v = *reinterpret_cast<const f32x4*>(&In[i]);
  ushort4v u; u[0]=f2bf(v[0]); u[1]=f2bf(v[1]); u[2]=f2bf(v[2]); u[3]=f2bf(v[3]);
  *reinterpret_cast<ushort4v*>(&InB[i]) = u;
}

// ---------------------------------------------------------------------------
// prep: pack BOTH W_hh and W_ih into per-(cb,wave,gate,ks) MFMA-B-fragment
// order (bf16) — identical mapping, two buffers. Also bias sum + h0 seed.
// Wpack[i]: e=i&7, l=(i>>3)&63, ks=(i>>9)&7, gate=(i>>12)&3, w=(i>>14)&3, cb=i>>16
//   -> W[gate*1024 + cb*16 + (l&15)][w*256 + ks*32 + (l>>4)*8 + e]
// grid 32768 x 256 covers 2 x 4M pack elements.
// ---------------------------------------------------------------------------
__global__ __launch_bounds__(256) void prep_kernel(
    const float* __restrict__ Whh, const float* __restrict__ Wih,
    const float* __restrict__ bih, const float* __restrict__ bhh,
    const float* __restrict__ h0, unsigned short* __restrict__ WpackHH,
    unsigned short* __restrict__ WpackIH, float* __restrict__ biasSum,
    unsigned short* __restrict__ hA){
  int i = blockIdx.x * 256 + threadIdx.x;
  if (i < G4) biasSum[i] = bih[i] + bhh[i];
  if (i < BATCH*HDIM) hA[i] = f2bf(h0[i]);
  int p = (i < G4*HDIM) ? i : i - G4*HDIM;
  int e = p & 7, l = (p >> 3) & 63, ks = (p >> 9) & 7;
  int gate = (p >> 12) & 3, w = (p >> 14) & 3, cb = p >> 16;
  int row = gate * HDIM + cb * 16 + (l & 15);
  int k = w * 256 + ks * 32 + (l >> 4) * 8 + e;
  if (i < G4*HDIM) WpackHH[p] = f2bf(Whh[row * HDIM + k]);
  else             WpackIH[p] = f2bf(Wih[row * IDIM + k]);
}

// ---------------------------------------------------------------------------
// FUSED recurrence: 256 blocks = (g: 4 batch-groups) x (cb: 64 col-blocks).
// Per step s: MFMA_hh on h(s) AND MFMA_ih on In(s+1) (x_gates fused, one step
// lookahead; In regs prefetched during the previous barrier slack). Both
// partial sets reduced through LDS after one barrier. Round-7 sync structure
// verbatim (per-group barrier, per-wave flag lines, sc0sc1 h exchange).
// ---------------------------------------------------------------------------
__global__ __launch_bounds__(256, 1) void recur_kernel(
    const float* __restrict__ h0, const float* __restrict__ c0,
    const float* __restrict__ ret, const unsigned short* __restrict__ WpackHH,
    const unsigned short* __restrict__ WpackIH, const unsigned short* __restrict__ InB,
    const float* __restrict__ biasSum, unsigned short* __restrict__ hA,
    unsigned short* __restrict__ hB, float* __restrict__ out,
    float* __restrict__ hc_out, unsigned* __restrict__ flags){
  __shared__ float partA[16 * 272];   // hh partials: [w*4+gate]*272 + m*17 + n
  __shared__ float partB[16 * 272];   // ih partials (same indexing)

  const int bid = blockIdx.x;
  const int cb = bid & 63, g = bid >> 6;
  const int tid = threadIdx.x;
  const int w = tid >> 6, l = tid & 63;
  const int lm = l & 15, lq = l >> 4;

  // W fragments for this (cb, wave): hh + ih, 4 gates x 8 ks each
  short8 WfH[4][8], WfI[4][8];
  {
    const short8* wph = reinterpret_cast<const short8*>(WpackHH)
                      + (size_t)(cb * 4 + w) * 2048 + l;
    const short8* wpi = reinterpret_cast<const short8*>(WpackIH)
                      + (size_t)(cb * 4 + w) * 2048 + l;
    #pragma unroll
    for (int gate = 0; gate < 4; ++gate)
      #pragma unroll
      for (int ks = 0; ks < 8; ++ks){
        WfH[gate][ks] = wph[(gate * 8 + ks) * 64];
        WfI[gate][ks] = wpi[(gate * 8 + ks) * 64];
      }
  }

  const int bl = tid >> 4, j = tid & 15;   // batch-in-group, col-in-block
  const int bglob = g * 16 + bl, jglob = cb * 16 + j;
  float c_reg = c0[bglob * HDIM + jglob];
  float h_reg = h0[bglob * HDIM + jglob];
  float r_reg = ret[jglob];
  float bias_reg[4];
  #pragma unroll
  for (int gate = 0; gate < 4; ++gate)
    bias_reg[gate] = biasSum[gate * 1024 + jglob];

  // per-lane In source offset (same fragment geometry as h)
  const size_t in_off = (size_t)(g * 16 + lm) * 1024 + w * 256 + lq * 8;

  unsigned* gflags = flags + g * 1024;   // one 64B line per block: [cb*16 + w]

  // ---- prologue: compute xv(0) from In(0) ----
  float xv[4];
  {
    short8 inr[8];
    const short8* ip = reinterpret_cast<const short8*>(InB + in_off);
    #pragma unroll
    for (int ks = 0; ks < 8; ++ks) inr[ks] = ip[ks * 4];   // ks*32 elems = 4 short8
    f32x4 accI[4];
    #pragma unroll
    for (int gate = 0; gate < 4; ++gate) accI[gate] = (f32x4){0.f,0.f,0.f,0.f};
    #pragma unroll
    for (int ks = 0; ks < 8; ++ks)
      #pragma unroll
      for (int gate = 0; gate < 4; ++gate)
        accI[gate] = mfma_bf16(inr[ks], WfI[gate][ks], accI[gate]);
    #pragma unroll
    for (int gate = 0; gate < 4; ++gate)
      #pragma unroll
      for (int r = 0; r < 4; ++r)
        partB[(w * 4 + gate) * 272 + (lq * 4 + r) * 17 + lm] = accI[gate][r];
    __syncthreads();
    #pragma unroll
    for (int gate = 0; gate < 4; ++gate){
      float sum = bias_reg[gate];
      #pragma unroll
      for (int ww = 0; ww < 4; ++ww)
        sum += partB[(ww * 4 + gate) * 272 + bl * 17 + j];
      xv[gate] = sum;
    }
    __syncthreads();   // protect partB before loop reuse
  }

  // preload In(1) fragment registers
  short8 inr[8];
  {
    const short8* ip = reinterpret_cast<const short8*>(InB + 65536 + in_off);
    #pragma unroll
    for (int ks = 0; ks < 8; ++ks) inr[ks] = ip[ks * 4];
  }

  for (int s = 0; s < S_LEN; ++s){
    const unsigned short* cur = (s & 1) ? hB : hA;
    unsigned short* nxt = (s & 1) ? hA : hB;

    // h load (LLC-coherent; internal vmcnt(0) also guarantees inr resident)
    const unsigned short* hp = cur + (size_t)(g * 16 + lm) * HDIM + w * 256 + lq * 8;
    short8 hr[8];
    load8_bypass(hp, hr);

    // MFMA hh (h(s) @ Whh) and ih (In(s+1) @ Wih -> xg(s+1))
    f32x4 accH[4], accI[4];
    #pragma unroll
    for (int gate = 0; gate < 4; ++gate){
      accH[gate] = (f32x4){0.f,0.f,0.f,0.f};
      accI[gate] = (f32x4){0.f,0.f,0.f,0.f};
    }
    #pragma unroll
    for (int ks = 0; ks < 8; ++ks){
      accH[0] = mfma_bf16(hr[ks], WfH[0][ks], accH[0]);
      accH[1] = mfma_bf16(hr[ks], WfH[1][ks], accH[1]);
      accH[2] = mfma_bf16(hr[ks], WfH[2][ks], accH[2]);
      accH[3] = mfma_bf16(hr[ks], WfH[3][ks], accH[3]);
      accI[0] = mfma_bf16(inr[ks], WfI[0][ks], accI[0]);
      accI[1] = mfma_bf16(inr[ks], WfI[1][ks], accI[1]);
      accI[2] = mfma_bf16(inr[ks], WfI[2][ks], accI[2]);
      accI[3] = mfma_bf16(inr[ks], WfI[3][ks], accI[3]);
    }

    // partials to LDS (D layout col=lane&15, row=(lane>>4)*4+r)
    #pragma unroll
    for (int gate = 0; gate < 4; ++gate)
      #pragma unroll
      for (int r = 0; r < 4; ++r){
        partA[(w * 4 + gate) * 272 + (lq * 4 + r) * 17 + lm] = accH[gate][r];
        partB[(w * 4 + gate) * 272 + (lq * 4 + r) * 17 + lm] = accI[gate][r];
      }
    __syncthreads();   // sync#1

    // reduce hh + xv(s) -> gates; update; h' store
    float gv[4];
    #pragma unroll
    for (int gate = 0; gate < 4; ++gate){
      float sum = xv[gate];
      #pragma unroll
      for (int ww = 0; ww < 4; ++ww)
        sum += partA[(ww * 4 + gate) * 272 + bl * 17 + j];
      gv[gate] = sum;
    }
    float ig = sigf(gv[0]), fg = sigf(gv[1]);
    float gt = tanhf_fast(gv[2]), og = sigf(gv[3]);
    float cy = fg * c_reg + ig * gt;
    float hy = og * tanhf_fast(cy);
    hy = r_reg * h_reg + (1.0f - r_reg) * hy;
    c_reg = cy; h_reg = hy;
    store_short_bypass(&nxt[bglob * HDIM + jglob], (unsigned)f2bf(hy));

    // reduce ih partials -> xv(s+1)
    #pragma unroll
    for (int gate = 0; gate < 4; ++gate){
      float sum = bias_reg[gate];
      #pragma unroll
      for (int ww = 0; ww < 4; ++ww)
        sum += partB[(ww * 4 + gate) * 272 + bl * 17 + j];
      xv[gate] = sum;
    }

    // ---- per-group barrier (round-7 structure) ----
    asm volatile("s_waitcnt vmcnt(0)" ::: "memory");  // own wave's h' at LLC
    const unsigned tgt = (unsigned)(s + 1);
    if (l == 0)
      store_dword_bypass(&gflags[cb * 16 + w], tgt);  // wave arrival

    // issue In(s+2) loads NOW (slack before poll: latency hides under barrier)
    {
      const int sn = (s + 2 < S_LEN) ? s + 2 : S_LEN - 1;
      const short8* ip = reinterpret_cast<const short8*>(InB + (size_t)sn * 65536 + in_off);
      #pragma unroll
      for (int ks = 0; ks < 8; ++ks) inr[ks] = ip[ks * 4];
    }

    if (w == 0){                    // wave 0: lane l polls block l's flag line
      const unsigned* fp = gflags + (l << 4);
      unsigned spins = 0;
      for (;;){
        uint4v f = load4_flags_bypass(fp);
        if (f[0] >= tgt && f[1] >= tgt && f[2] >= tgt && f[3] >= tgt) break;
        __builtin_amdgcn_s_sleep(1);
        if (++spins > 50000000u) break;   // safety bailout, never expected
      }
    }
    __syncthreads();   // sync#2: all waves see the barrier passed

    // out[] store AFTER the barrier: retires under next step's loads
    out[((size_t)s * BATCH + bglob) * HDIM + jglob] = h_reg;
  }

  hc_out[bglob * HDIM + jglob] = h_reg;
  hc_out[BATCH * HDIM + bglob * HDIM + jglob] = c_reg;
}

// ---------------------------------------------------------------------------
extern "C" void kernel_launch(void* const* d_in, const int* in_sizes, int n_in,
                              void* d_out, int out_size, void* d_ws, size_t ws_size,
                              hipStream_t stream){
  const float* In  = (const float*)d_in[0];
  const float* h0  = (const float*)d_in[1];
  const float* c0  = (const float*)d_in[2];
  const float* Wih = (const float*)d_in[3];
  const float* Whh = (const float*)d_in[4];
  const float* bih = (const float*)d_in[5];
  const float* bhh = (const float*)d_in[6];
  const float* ret = (const float*)d_in[7];
  float* out = (float*)d_out;

  char* ws = (char*)d_ws;
  const size_t off_flags = 0;                          // 16 KB (4 groups x 4 KB)
  const size_t off_bias  = 16384;                      // 16 KB
  const size_t off_hA    = 32768;                      // 128 KB
  const size_t off_hB    = off_hA + 131072;
  const size_t off_wph   = off_hB + 131072;            // 8 MB (Whh pack)
  const size_t off_wpi   = off_wph + 8388608;          // 8 MB (Wih pack)
  const size_t off_inb   = off_wpi + 8388608;          // 64 MB (In bf16)
  const size_t need      = off_inb + 67108864;

  unsigned*       flags   = (unsigned*)(ws + off_flags);
  float*          biasSum = (float*)(ws + off_bias);
  unsigned short* hA      = (unsigned short*)(ws + off_hA);
  unsigned short* hB      = (unsigned short*)(ws + off_hB);
  unsigned short* WpackHH = (unsigned short*)(ws + off_wph);
  unsigned short* WpackIH = (unsigned short*)(ws + off_wpi);
  unsigned short* InB     = (unsigned short*)(ws + off_inb);

  if (ws_size < need) return;  // cannot run; fail validation loudly

  (void)hipMemsetAsync(ws + off_flags, 0, 16384, stream);
  convert_kernel<<<32768, 256, 0, stream>>>(In, InB);
  prep_kernel<<<32768, 256, 0, stream>>>(Whh, Wih, bih, bhh, h0,
                                         WpackHH, WpackIH, biasSum, hA);

  float* hc_out = out + (size_t)S_LEN * BATCH * HDIM;
  recur_kernel<<<NBLK, 256, 0, stream>>>(h0, c0, ret, WpackHH, WpackIH, InB,
                                         biasSum, hA, hB, out, hc_out, flags);
}